// Round 13
// baseline (464.811 us; speedup 1.0000x reference)
//
#include <hip/hip_runtime.h>

#define NN 100000
#define EE 600000
#define NQ 200000
#define HID 128
#define NL 4
#define BN_EPS 1e-5f
#define ECAP 1280  // LDS edge-staging capacity; fallback to global if exceeded

typedef __attribute__((ext_vector_type(8))) short short8;
typedef __attribute__((ext_vector_type(4))) float f32x4;

__device__ __forceinline__ float gelu_f(float v) {
    return 0.5f * v * (1.0f + erff(v * 0.70710678118654752f));
}
__device__ __forceinline__ unsigned short f2bf(float f) {
    unsigned int x = __float_as_uint(f);
    unsigned int r = (x + 0x7FFFu + ((x >> 16) & 1u)) >> 16;
    return (unsigned short)r;
}
__device__ __forceinline__ float bf2f(unsigned short u) {
    return __uint_as_float(((unsigned int)u) << 16);
}

// ---------------- small utility kernels ----------------

__global__ void k_zero_int(int* __restrict__ p, int n) {
    int i = blockIdx.x * blockDim.x + threadIdx.x;
    if (i < n) p[i] = 0;
}

// fused: bf16 convert (all elements) + dst-degree histogram (first EE threads)
__global__ void k_cvthist(const float* __restrict__ x, unsigned int* __restrict__ o, int n2,
                          const int* __restrict__ ei, int* __restrict__ cnt) {
    int i = blockIdx.x * blockDim.x + threadIdx.x;
    if (i < n2) {
        float2 v = ((const float2*)x)[i];
        o[i] = (unsigned int)f2bf(v.x) | ((unsigned int)f2bf(v.y) << 16);
    }
    if (i < EE) atomicAdd(&cnt[ei[EE + i]], 1);  // int atomics: deterministic result
}

__global__ void k_bninit(float* __restrict__ sc) {
    int i = threadIdx.x;
    sc[i] = (i < 128) ? 1.0f : 0.0f;
}

// ---------------- CSR build (deterministic) ----------------

__global__ void k_scan1(const int* __restrict__ cnt, int* __restrict__ rp,
                        int* __restrict__ bsum, int n) {
    __shared__ int sh[256];
    const int tid = threadIdx.x;
    const int base = blockIdx.x * 1024;
    int v[4];
    int s = 0;
    #pragma unroll
    for (int j = 0; j < 4; ++j) {
        int idx = base + tid * 4 + j;
        v[j] = (idx < n) ? cnt[idx] : 0;
        s += v[j];
    }
    sh[tid] = s;
    __syncthreads();
    for (int off = 1; off < 256; off <<= 1) {
        int t = (tid >= off) ? sh[tid - off] : 0;
        __syncthreads();
        sh[tid] += t;
        __syncthreads();
    }
    int run = sh[tid] - s;
    #pragma unroll
    for (int j = 0; j < 4; ++j) {
        int idx = base + tid * 4 + j;
        if (idx < n) rp[idx] = run;
        run += v[j];
    }
    if (tid == 255) bsum[blockIdx.x] = sh[255];
}

__global__ void k_scan2(int* __restrict__ bsum, int nb) {
    __shared__ int sh[256];
    const int tid = threadIdx.x;
    int v = (tid < nb) ? bsum[tid] : 0;
    sh[tid] = v;
    __syncthreads();
    for (int off = 1; off < 256; off <<= 1) {
        int t = (tid >= off) ? sh[tid - off] : 0;
        __syncthreads();
        sh[tid] += t;
        __syncthreads();
    }
    if (tid < nb) bsum[tid] = sh[tid] - v;
}

__global__ void k_scan3(int* __restrict__ rp, const int* __restrict__ bsum,
                        int* __restrict__ cnt, int n) {
    int i = blockIdx.x * blockDim.x + threadIdx.x;
    if (i < n) {
        rp[i] += bsum[i >> 10];
        cnt[i] = 0;
    }
    if (i == 0) rp[n] = EE;
}

// slot assignment is atomic-order-dependent; only edge ids are stored here
__global__ void k_fill(const int* __restrict__ ei, const int* __restrict__ rp,
                       int* __restrict__ cur, int* __restrict__ eord) {
    int e = blockIdx.x * blockDim.x + threadIdx.x;
    if (e < EE) {
        int d = ei[EE + e];
        int p = rp[d] + atomicAdd(&cur[d], 1);
        eord[p] = e;
    }
}

// canonicalize: sort each segment by edge id, then materialize csrc/cea/wdeg.
__global__ void k_sortfill(const int* __restrict__ ei, const float* __restrict__ ea,
                           const int* __restrict__ rp, int* __restrict__ eord,
                           int* __restrict__ csrc, float* __restrict__ cea,
                           float* __restrict__ wdeg) {
    int n = blockIdx.x * blockDim.x + threadIdx.x;
    if (n >= NN) return;
    const int s0 = rp[n], s1 = rp[n + 1];
    for (int i = s0 + 1; i < s1; ++i) {
        int key = eord[i];
        int j = i - 1;
        while (j >= s0 && eord[j] > key) { eord[j + 1] = eord[j]; --j; }
        eord[j + 1] = key;
    }
    float s = 0.f;
    for (int i = s0; i < s1; ++i) {
        const int e = eord[i];
        csrc[i] = ei[e];
        const float w = ea[e];
        cea[i] = w;
        s += w;
    }
    wdeg[n] = s;
}

// ---------------- weight prep (parallel, BN affine folded, fragment layout) ----------------
// Fragment-linear layout: fragment (kc = k>>5, nb = n>>4):
//   W[(kc*8+nb)*512 + ((k>>3)&3)*16*8 + (n&15)*8 + (k&7)]
// A wave's B-fragment load is one coalesced 1KB short8 read (L2-resident).

__global__ void k_wprep(const float* __restrict__ relw, const float* __restrict__ rootw,
                        const float* __restrict__ relb, const float* __restrict__ sc,
                        unsigned short* __restrict__ Wtf, float* __restrict__ bias2,
                        float* __restrict__ brel) {
    __shared__ float shb[256];
    const int n = blockIdx.x;
    const int k = threadIdx.x;
    const float s = sc[k & 127];
    const float w = (k < 128) ? relw[(size_t)k * HID + n] : rootw[(size_t)(k - 128) * HID + n];
    const int nb = n >> 4, l15 = n & 15;
    const int kc = k >> 5, kg = (k >> 3) & 3, e = k & 7;
    Wtf[((size_t)(kc * 8 + nb) * 512) + (kg * 16 + l15) * 8 + e] = f2bf(s * w);
    shb[k] = sc[128 + (k & 127)] * w;
    __syncthreads();
    #pragma unroll
    for (int off = 64; off >= 1; off >>= 1) {
        if (k < off) shb[k] += shb[k + off];
        else if (k >= 128 && k < 128 + off) shb[k] += shb[k + off];
        __syncthreads();
    }
    if (k == 0) brel[n] = shb[0];
    if (k == 128) bias2[n] = relb[n] + shb[128];
}

__global__ void k_mlpprep(const float* __restrict__ w1, const float* __restrict__ b1,
                          const float* __restrict__ sc, unsigned short* __restrict__ Wtmf,
                          float* __restrict__ b1v) {
    __shared__ float shb[256];
    const int n = blockIdx.x;
    const int k = threadIdx.x;
    const float w = w1[(size_t)k * HID + n];
    const int nb = n >> 4, l15 = n & 15;
    const int kc = k >> 5, kg = (k >> 3) & 3, e = k & 7;
    Wtmf[((size_t)(kc * 8 + nb) * 512) + (kg * 16 + l15) * 8 + e] = f2bf(sc[k & 127] * w);
    shb[k] = sc[128 + (k & 127)] * w;
    __syncthreads();
    #pragma unroll
    for (int off = 128; off >= 1; off >>= 1) {
        if (k < off) shb[k] += shb[k + off];
        __syncthreads();
    }
    if (k == 0) b1v[n] = b1[n] + shb[0];
}

// ---------------- fused gather + MFMA conv GEMM ----------------
// Gather: group-per-row, ILP-4 — each 16-lane group owns a row and runs 4
// independent edge chains (16 chains/wave, 2x round-12 loads in flight).
// Fixed edge->chain assignment + fixed combine tree = deterministic.

__global__ __launch_bounds__(512, 6) void k_gemm2(
    const unsigned short* __restrict__ hprev, const int* __restrict__ csrc,
    const float* __restrict__ cea, const int* __restrict__ rp,
    const unsigned short* __restrict__ Wtf, const float* __restrict__ bias2,
    const float* __restrict__ brel, const float* __restrict__ wdeg,
    unsigned short* __restrict__ hnext, float* __restrict__ bnpart,
    int nrows, int nblk) {
    __shared__ unsigned short As[128 * 128];
    __shared__ float psb[8 * 64];
    __shared__ float pqb[8 * 64];
    __shared__ int2 ewi[ECAP];
    __shared__ int rps[132];
    const int tid = threadIdx.x;
    const int rb = blockIdx.x * 128;

    const int lane = tid & 63;
    const int wid = tid >> 6;
    const int wm = wid >> 1, wn = wid & 1;

    // stage row bounds + interleaved edge data
    if (tid < 129) {
        int nn = rb + tid;
        rps[tid] = rp[nn < nrows ? nn : nrows];
    }
    __syncthreads();
    const int e0 = rps[0];
    const int ne = rps[128] - e0;
    const bool useLds = (ne <= ECAP);
    if (useLds) {
        for (int i = tid; i < ne; i += 512) {
            ewi[i] = make_int2(csrc[e0 + i], __float_as_int(cea[e0 + i]));
        }
    }

    f32x4 acc[2][4];
    #pragma unroll
    for (int mf = 0; mf < 2; ++mf)
        #pragma unroll
        for (int nf = 0; nf < 4; ++nf) acc[mf][nf] = (f32x4){0.f, 0.f, 0.f, 0.f};

    #pragma unroll
    for (int s = 0; s < 2; ++s) {
        __syncthreads();
        if (s == 0) {
            // ---- gather-staging: group g owns row (wid*16 + rs*4 + g), ILP-4 ----
            const int g = lane >> 4;        // row-within-set 0..3
            const int cl = lane & 15;       // 16B chunk within the row
            #pragma unroll
            for (int rs = 0; rs < 4; ++rs) {
                const int r = wid * 16 + rs * 4 + g;
                const int s0 = rps[r] - e0, s1 = rps[r + 1] - e0;
                float ac[4][8];
                #pragma unroll
                for (int c = 0; c < 4; ++c)
                    #pragma unroll
                    for (int j = 0; j < 8; ++j) ac[c][j] = 0.f;
                for (int i = s0; i < s1; i += 4) {
                    int srcs[4];
                    float ws[4];
                    #pragma unroll
                    for (int c = 0; c < 4; ++c) {
                        const int ii = i + c;
                        const bool has = ii < s1;
                        if (useLds) {
                            const int2 p = ewi[has ? ii : i];
                            srcs[c] = p.x;
                            ws[c] = has ? __int_as_float(p.y) : 0.f;
                        } else {
                            srcs[c] = csrc[e0 + (has ? ii : i)];
                            ws[c] = has ? cea[e0 + ii] : 0.f;
                        }
                    }
                    #pragma unroll
                    for (int c = 0; c < 4; ++c) {
                        const uint4 v = *(const uint4*)(hprev + (size_t)srcs[c] * HID + cl * 8);
                        const float w = ws[c];
                        ac[c][0] += bf2f((unsigned short)(v.x)) * w;
                        ac[c][1] += bf2f((unsigned short)(v.x >> 16)) * w;
                        ac[c][2] += bf2f((unsigned short)(v.y)) * w;
                        ac[c][3] += bf2f((unsigned short)(v.y >> 16)) * w;
                        ac[c][4] += bf2f((unsigned short)(v.z)) * w;
                        ac[c][5] += bf2f((unsigned short)(v.z >> 16)) * w;
                        ac[c][6] += bf2f((unsigned short)(v.w)) * w;
                        ac[c][7] += bf2f((unsigned short)(v.w >> 16)) * w;
                    }
                }
                // fixed combine tree — deterministic
                float rr[8];
                #pragma unroll
                for (int j = 0; j < 8; ++j)
                    rr[j] = (ac[0][j] + ac[1][j]) + (ac[2][j] + ac[3][j]);
                uint4 o;
                o.x = (unsigned int)f2bf(rr[0]) | ((unsigned int)f2bf(rr[1]) << 16);
                o.y = (unsigned int)f2bf(rr[2]) | ((unsigned int)f2bf(rr[3]) << 16);
                o.z = (unsigned int)f2bf(rr[4]) | ((unsigned int)f2bf(rr[5]) << 16);
                o.w = (unsigned int)f2bf(rr[6]) | ((unsigned int)f2bf(rr[7]) << 16);
                const int p = cl ^ (r & 7);  // swizzled chunk position
                *(uint4*)(As + r * 128 + p * 8) = o;
            }
        } else {
            // ---- contiguous hprev staging (root path) ----
            #pragma unroll
            for (int i = 0; i < 4; ++i) {
                const int r = i * 32 + (tid >> 4);
                const int p = tid & 15;
                const int gr = min(rb + r, nrows - 1);
                const int gc = p ^ (r & 7);
                const uint4 v = *(const uint4*)(hprev + (size_t)gr * 128 + gc * 8);
                *(uint4*)(As + r * 128 + p * 8) = v;
            }
        }
        __syncthreads();
        #pragma unroll
        for (int kk = 0; kk < 4; ++kk) {
            short8 a[2], b[4];
            #pragma unroll
            for (int mf = 0; mf < 2; ++mf) {
                const int r = wm * 32 + mf * 16 + (lane & 15);
                const int p = (kk * 4 + (lane >> 4)) ^ (r & 7);
                a[mf] = *(const short8*)(As + r * 128 + p * 8);
            }
            #pragma unroll
            for (int nf = 0; nf < 4; ++nf) {
                // fragment-linear, coalesced, L2-resident
                b[nf] = *(const short8*)(Wtf + ((size_t)((s * 4 + kk) * 8 + wn * 4 + nf) * 512)
                                               + lane * 8);
            }
            #pragma unroll
            for (int mf = 0; mf < 2; ++mf)
                #pragma unroll
                for (int nf = 0; nf < 4; ++nf)
                    acc[mf][nf] = __builtin_amdgcn_mfma_f32_16x16x32_bf16(
                        a[mf], b[nf], acc[mf][nf], 0, 0, 0);
        }
    }

    // epilogue: bias + wdeg*brel, gelu, direct bf16 store, BN partials
    int colv[4];
    float biasv[4], brelv[4];
    #pragma unroll
    for (int nf = 0; nf < 4; ++nf) {
        colv[nf] = wn * 64 + nf * 16 + (lane & 15);
        biasv[nf] = bias2[colv[nf]];
        brelv[nf] = brel[colv[nf]];
    }
    float ps[4] = {0.f, 0.f, 0.f, 0.f}, pq[4] = {0.f, 0.f, 0.f, 0.f};
    #pragma unroll
    for (int mf = 0; mf < 2; ++mf) {
        #pragma unroll
        for (int reg = 0; reg < 4; ++reg) {
            const int gm = rb + wm * 32 + mf * 16 + (lane >> 4) * 4 + reg;
            const bool valid = gm < nrows;
            const float wd = valid ? wdeg[gm] : 0.f;
            #pragma unroll
            for (int nf = 0; nf < 4; ++nf) {
                const float hv = gelu_f(acc[mf][nf][reg] + biasv[nf] + wd * brelv[nf]);
                if (valid) {
                    hnext[(size_t)gm * 128 + colv[nf]] = f2bf(hv);
                    ps[nf] += hv;
                    pq[nf] += hv * hv;
                }
            }
        }
    }
    #pragma unroll
    for (int nf = 0; nf < 4; ++nf) {
        ps[nf] += __shfl_xor(ps[nf], 16); ps[nf] += __shfl_xor(ps[nf], 32);
        pq[nf] += __shfl_xor(pq[nf], 16); pq[nf] += __shfl_xor(pq[nf], 32);
        if ((lane >> 4) == 0) {
            psb[wid * 64 + nf * 16 + (lane & 15)] = ps[nf];
            pqb[wid * 64 + nf * 16 + (lane & 15)] = pq[nf];
        }
    }
    __syncthreads();
    if (tid < 128) {
        const int wnh = tid >> 6;
        const int c64 = tid & 63;
        float s = 0.f, q = 0.f;
        #pragma unroll
        for (int w = 0; w < 4; ++w) {  // fixed order across waves
            s += psb[(w * 2 + wnh) * 64 + c64];
            q += pqb[(w * 2 + wnh) * 64 + c64];
        }
        bnpart[(size_t)tid * nblk + blockIdx.x] = s;
        bnpart[(size_t)(128 + tid) * nblk + blockIdx.x] = q;
    }
}

// fused parallel deterministic BN reduce + finalize: one block per channel
__global__ void k_bnredfin(const float* __restrict__ bnpart, int nblk,
                           const float* __restrict__ g, const float* __restrict__ b,
                           float* __restrict__ sc) {
    __shared__ float sh[256];
    __shared__ float sh2[256];
    const int tid = threadIdx.x;
    const int col = blockIdx.x;  // 0..127
    float s = 0.f, q = 0.f;
    for (int i = tid; i < nblk; i += 256) {
        s += bnpart[(size_t)col * nblk + i];
        q += bnpart[(size_t)(128 + col) * nblk + i];
    }
    sh[tid] = s;
    sh2[tid] = q;
    __syncthreads();
    #pragma unroll
    for (int off = 128; off >= 1; off >>= 1) {
        if (tid < off) { sh[tid] += sh[tid + off]; sh2[tid] += sh2[tid + off]; }
        __syncthreads();
    }
    if (tid == 0) {
        const float inv_n = 1.0f / (float)NN;
        const float mean = sh[0] * inv_n;
        const float var = sh2[0] * inv_n - mean * mean;
        const float scale = g[col] * rsqrtf(var + BN_EPS);
        sc[col] = scale;
        sc[128 + col] = b[col] - mean * scale;
    }
}

// ---------------- MFMA edge MLP (no Bs staging; deterministic row reduce) ----------------

__global__ __launch_bounds__(512, 6) void k_mlp2(
    const unsigned short* __restrict__ xf, const int* __restrict__ eli,
    const unsigned short* __restrict__ Wtmf, const float* __restrict__ b1v,
    const float* __restrict__ w2, const float* __restrict__ b2,
    float* __restrict__ out, int nq) {
    __shared__ unsigned short As[128 * 128];
    __shared__ int sidx[256];
    __shared__ float rowred2[2][128];
    const int tid = threadIdx.x;
    const int qb = blockIdx.x * 128;
    if (tid < 256) {
        const int rr = tid & 127;
        const int q = qb + rr;
        sidx[tid] = (q < nq) ? eli[(tid >> 7) * NQ + q] : 0;
    }
    __syncthreads();

    const int lane = tid & 63;
    const int wid = tid >> 6;
    const int wm = wid >> 1, wn = wid & 1;

    f32x4 acc[2][4];
    #pragma unroll
    for (int mf = 0; mf < 2; ++mf)
        #pragma unroll
        for (int nf = 0; nf < 4; ++nf) acc[mf][nf] = (f32x4){0.f, 0.f, 0.f, 0.f};

    #pragma unroll
    for (int s = 0; s < 2; ++s) {
        if (s) __syncthreads();
        #pragma unroll
        for (int i = 0; i < 4; ++i) {
            const int r = i * 32 + (tid >> 4);
            const int p = tid & 15;
            const int node = sidx[s * 128 + r];
            const int gc = p ^ (r & 7);
            const uint4 v = *(const uint4*)(xf + (size_t)node * 128 + gc * 8);
            *(uint4*)(As + r * 128 + p * 8) = v;
        }
        __syncthreads();
        #pragma unroll
        for (int kk = 0; kk < 4; ++kk) {
            short8 a[2], b[4];
            #pragma unroll
            for (int mf = 0; mf < 2; ++mf) {
                const int r = wm * 32 + mf * 16 + (lane & 15);
                const int p = (kk * 4 + (lane >> 4)) ^ (r & 7);
                a[mf] = *(const short8*)(As + r * 128 + p * 8);
            }
            #pragma unroll
            for (int nf = 0; nf < 4; ++nf) {
                b[nf] = *(const short8*)(Wtmf + ((size_t)((s * 4 + kk) * 8 + wn * 4 + nf) * 512)
                                               + lane * 8);
            }
            #pragma unroll
            for (int mf = 0; mf < 2; ++mf)
                #pragma unroll
                for (int nf = 0; nf < 4; ++nf)
                    acc[mf][nf] = __builtin_amdgcn_mfma_f32_16x16x32_bf16(
                        a[mf], b[nf], acc[mf][nf], 0, 0, 0);
        }
    }

    int colv[4];
    float w2v[4], b1c[4];
    #pragma unroll
    for (int nf = 0; nf < 4; ++nf) {
        colv[nf] = wn * 64 + nf * 16 + (lane & 15);
        w2v[nf] = w2[colv[nf]];
        b1c[nf] = b1v[colv[nf]];
    }
    #pragma unroll
    for (int mf = 0; mf < 2; ++mf) {
        #pragma unroll
        for (int reg = 0; reg < 4; ++reg) {
            float part = 0.f;
            #pragma unroll
            for (int nf = 0; nf < 4; ++nf)
                part += gelu_f(acc[mf][nf][reg] + b1c[nf]) * w2v[nf];
            part += __shfl_xor(part, 1);
            part += __shfl_xor(part, 2);
            part += __shfl_xor(part, 4);
            part += __shfl_xor(part, 8);
            if ((lane & 15) == 0) {
                const int lr = wm * 32 + mf * 16 + (lane >> 4) * 4 + reg;
                rowred2[wn][lr] = part;  // unique writer per (wn, lr)
            }
        }
    }
    __syncthreads();
    if (tid < 128) {
        const int q = qb + tid;
        if (q < nq)
            out[q] = 1.0f / (1.0f + expf(-(rowred2[0][tid] + rowred2[1][tid] + b2[0])));
    }
}

// ---------------- launcher ----------------

extern "C" void kernel_launch(void* const* d_in, const int* in_sizes, int n_in,
                              void* d_out, int out_size, void* d_ws, size_t ws_size,
                              hipStream_t stream) {
    const float* x_in = (const float*)d_in[0];
    const int* ei = (const int*)d_in[1];
    const float* ea = (const float*)d_in[2];
    const int* eli = (const int*)d_in[3];
    const float* rel_w = (const float*)d_in[4];
    const float* rel_b = (const float*)d_in[5];
    const float* root_w = (const float*)d_in[6];
    const float* bn_g = (const float*)d_in[7];
    const float* bn_b = (const float*)d_in[8];
    const float* w1 = (const float*)d_in[9];
    const float* b1 = (const float*)d_in[10];
    const float* w2 = (const float*)d_in[11];
    const float* b2 = (const float*)d_in[12];
    float* out = (float*)d_out;

    char* ws = (char*)d_ws;
    size_t off = 0;
    auto alloc = [&](size_t bytes) -> void* {
        void* p = ws + off;
        off = (off + bytes + 255) & ~(size_t)255;
        return p;
    };
    const int nblk_gemm = (NN + 127) / 128;  // 782
    unsigned short* hb0 = (unsigned short*)alloc(2ull * NN * HID);
    unsigned short* hb1 = (unsigned short*)alloc(2ull * NN * HID);
    int* eord = (int*)alloc(sizeof(int) * EE);
    int* csrc = (int*)alloc(sizeof(int) * EE);
    float* cea = (float*)alloc(sizeof(float) * EE);
    int* rp = (int*)alloc(sizeof(int) * (NN + 1));
    int* cnt = (int*)alloc(sizeof(int) * NN);
    int* bsum = (int*)alloc(sizeof(int) * 256);
    float* wdeg = (float*)alloc(sizeof(float) * NN);
    float* bnpart = (float*)alloc(sizeof(float) * 256 * (size_t)nblk_gemm);
    float* bnsc = (float*)alloc(sizeof(float) * 256);
    unsigned short* Wtf = (unsigned short*)alloc(2ull * 128 * 256);
    unsigned short* Wtmf = (unsigned short*)alloc(2ull * 128 * 256);
    float* bias2 = (float*)alloc(sizeof(float) * 128);
    float* brel = (float*)alloc(sizeof(float) * 128);
    float* b1v = (float*)alloc(sizeof(float) * 128);
    (void)ws_size;

    const int nb_scan = (NN + 1023) / 1024;

    // CSR count must be zeroed before the fused cvt+hist
    k_zero_int<<<(NN + 255) / 256, 256, 0, stream>>>(cnt, NN);
    // fused input->bf16 convert + degree histogram
    k_cvthist<<<(NN * 64 + 255) / 256, 256, 0, stream>>>(x_in, (unsigned int*)hb0, NN * 64,
                                                         ei, cnt);
    k_scan1<<<nb_scan, 256, 0, stream>>>(cnt, rp, bsum, NN);
    k_scan2<<<1, 256, 0, stream>>>(bsum, nb_scan);
    k_scan3<<<(NN + 255) / 256, 256, 0, stream>>>(rp, bsum, cnt, NN);
    k_fill<<<(EE + 255) / 256, 256, 0, stream>>>(ei, rp, cnt, eord);
    k_sortfill<<<(NN + 255) / 256, 256, 0, stream>>>(ei, ea, rp, eord, csrc, cea, wdeg);
    k_bninit<<<1, 256, 0, stream>>>(bnsc);

    unsigned short* hcur = hb0;
    unsigned short* bufs[2] = {hb1, hb0};
    for (int l = 0; l < NL; ++l) {
        unsigned short* hnext = bufs[l & 1];
        k_wprep<<<128, 256, 0, stream>>>(rel_w + (size_t)l * HID * HID,
                                         root_w + (size_t)l * HID * HID,
                                         rel_b + (size_t)l * HID, bnsc, Wtf, bias2, brel);
        k_gemm2<<<nblk_gemm, 512, 0, stream>>>(hcur, csrc, cea, rp, Wtf, bias2, brel, wdeg,
                                               hnext, bnpart, NN, nblk_gemm);
        k_bnredfin<<<128, 256, 0, stream>>>(bnpart, nblk_gemm,
                                            bn_g + (size_t)l * HID, bn_b + (size_t)l * HID, bnsc);
        hcur = hnext;
    }

    k_mlpprep<<<128, 256, 0, stream>>>(w1, b1, bnsc, Wtmf, b1v);
    k_mlp2<<<(NQ + 127) / 128, 512, 0, stream>>>(hcur, eli, Wtmf, b1v, w2, b2, out, NQ);
}

// Round 14
// 418.753 us; speedup vs baseline: 1.1100x; 1.1100x over previous
//
#include <hip/hip_runtime.h>

#define NN 100000
#define EE 600000
#define NQ 200000
#define HID 128
#define NL 4
#define BN_EPS 1e-5f
#define ECAP 1280  // LDS edge-staging capacity; fallback to global if exceeded

typedef __attribute__((ext_vector_type(8))) short short8;
typedef __attribute__((ext_vector_type(4))) float f32x4;

__device__ __forceinline__ float gelu_f(float v) {
    return 0.5f * v * (1.0f + erff(v * 0.70710678118654752f));
}
__device__ __forceinline__ unsigned short f2bf(float f) {
    unsigned int x = __float_as_uint(f);
    unsigned int r = (x + 0x7FFFu + ((x >> 16) & 1u)) >> 16;
    return (unsigned short)r;
}
__device__ __forceinline__ float bf2f(unsigned short u) {
    return __uint_as_float(((unsigned int)u) << 16);
}

// ---------------- small utility kernels ----------------

__global__ void k_zero_int(int* __restrict__ p, int n) {
    int i = blockIdx.x * blockDim.x + threadIdx.x;
    if (i < n) p[i] = 0;
}

// fused: bf16 convert (all elements) + dst-degree histogram (first EE threads)
__global__ void k_cvthist(const float* __restrict__ x, unsigned int* __restrict__ o, int n2,
                          const int* __restrict__ ei, int* __restrict__ cnt) {
    int i = blockIdx.x * blockDim.x + threadIdx.x;
    if (i < n2) {
        float2 v = ((const float2*)x)[i];
        o[i] = (unsigned int)f2bf(v.x) | ((unsigned int)f2bf(v.y) << 16);
    }
    if (i < EE) atomicAdd(&cnt[ei[EE + i]], 1);  // int atomics: deterministic result
}

__global__ void k_bninit(float* __restrict__ sc) {
    int i = threadIdx.x;
    sc[i] = (i < 128) ? 1.0f : 0.0f;
}

// ---------------- CSR build (deterministic) ----------------

__global__ void k_scan1(const int* __restrict__ cnt, int* __restrict__ rp,
                        int* __restrict__ bsum, int n) {
    __shared__ int sh[256];
    const int tid = threadIdx.x;
    const int base = blockIdx.x * 1024;
    int v[4];
    int s = 0;
    #pragma unroll
    for (int j = 0; j < 4; ++j) {
        int idx = base + tid * 4 + j;
        v[j] = (idx < n) ? cnt[idx] : 0;
        s += v[j];
    }
    sh[tid] = s;
    __syncthreads();
    for (int off = 1; off < 256; off <<= 1) {
        int t = (tid >= off) ? sh[tid - off] : 0;
        __syncthreads();
        sh[tid] += t;
        __syncthreads();
    }
    int run = sh[tid] - s;
    #pragma unroll
    for (int j = 0; j < 4; ++j) {
        int idx = base + tid * 4 + j;
        if (idx < n) rp[idx] = run;
        run += v[j];
    }
    if (tid == 255) bsum[blockIdx.x] = sh[255];
}

__global__ void k_scan2(int* __restrict__ bsum, int nb) {
    __shared__ int sh[256];
    const int tid = threadIdx.x;
    int v = (tid < nb) ? bsum[tid] : 0;
    sh[tid] = v;
    __syncthreads();
    for (int off = 1; off < 256; off <<= 1) {
        int t = (tid >= off) ? sh[tid - off] : 0;
        __syncthreads();
        sh[tid] += t;
        __syncthreads();
    }
    if (tid < nb) bsum[tid] = sh[tid] - v;
}

__global__ void k_scan3(int* __restrict__ rp, const int* __restrict__ bsum,
                        int* __restrict__ cnt, int n) {
    int i = blockIdx.x * blockDim.x + threadIdx.x;
    if (i < n) {
        rp[i] += bsum[i >> 10];
        cnt[i] = 0;
    }
    if (i == 0) rp[n] = EE;
}

// slot assignment is atomic-order-dependent; only edge ids are stored here
__global__ void k_fill(const int* __restrict__ ei, const int* __restrict__ rp,
                       int* __restrict__ cur, int* __restrict__ eord) {
    int e = blockIdx.x * blockDim.x + threadIdx.x;
    if (e < EE) {
        int d = ei[EE + e];
        int p = rp[d] + atomicAdd(&cur[d], 1);
        eord[p] = e;
    }
}

// canonicalize: sort each segment by edge id, then materialize csrc/cea/wdeg.
__global__ void k_sortfill(const int* __restrict__ ei, const float* __restrict__ ea,
                           const int* __restrict__ rp, int* __restrict__ eord,
                           int* __restrict__ csrc, float* __restrict__ cea,
                           float* __restrict__ wdeg) {
    int n = blockIdx.x * blockDim.x + threadIdx.x;
    if (n >= NN) return;
    const int s0 = rp[n], s1 = rp[n + 1];
    for (int i = s0 + 1; i < s1; ++i) {
        int key = eord[i];
        int j = i - 1;
        while (j >= s0 && eord[j] > key) { eord[j + 1] = eord[j]; --j; }
        eord[j + 1] = key;
    }
    float s = 0.f;
    for (int i = s0; i < s1; ++i) {
        const int e = eord[i];
        csrc[i] = ei[e];
        const float w = ea[e];
        cea[i] = w;
        s += w;
    }
    wdeg[n] = s;
}

// ---------------- weight prep (parallel, BN affine folded, fragment layout) ----------------
// Fragment-linear layout: fragment (kc = k>>5, nb = n>>4):
//   W[(kc*8+nb)*512 + ((k>>3)&3)*16*8 + (n&15)*8 + (k&7)]
// A wave's B-fragment load is one coalesced 1KB short8 read (L2-resident).

__global__ void k_wprep(const float* __restrict__ relw, const float* __restrict__ rootw,
                        const float* __restrict__ relb, const float* __restrict__ sc,
                        unsigned short* __restrict__ Wtf, float* __restrict__ bias2,
                        float* __restrict__ brel) {
    __shared__ float shb[256];
    const int n = blockIdx.x;
    const int k = threadIdx.x;
    const float s = sc[k & 127];
    const float w = (k < 128) ? relw[(size_t)k * HID + n] : rootw[(size_t)(k - 128) * HID + n];
    const int nb = n >> 4, l15 = n & 15;
    const int kc = k >> 5, kg = (k >> 3) & 3, e = k & 7;
    Wtf[((size_t)(kc * 8 + nb) * 512) + (kg * 16 + l15) * 8 + e] = f2bf(s * w);
    shb[k] = sc[128 + (k & 127)] * w;
    __syncthreads();
    #pragma unroll
    for (int off = 64; off >= 1; off >>= 1) {
        if (k < off) shb[k] += shb[k + off];
        else if (k >= 128 && k < 128 + off) shb[k] += shb[k + off];
        __syncthreads();
    }
    if (k == 0) brel[n] = shb[0];
    if (k == 128) bias2[n] = relb[n] + shb[128];
}

__global__ void k_mlpprep(const float* __restrict__ w1, const float* __restrict__ b1,
                          const float* __restrict__ sc, unsigned short* __restrict__ Wtmf,
                          float* __restrict__ b1v) {
    __shared__ float shb[256];
    const int n = blockIdx.x;
    const int k = threadIdx.x;
    const float w = w1[(size_t)k * HID + n];
    const int nb = n >> 4, l15 = n & 15;
    const int kc = k >> 5, kg = (k >> 3) & 3, e = k & 7;
    Wtmf[((size_t)(kc * 8 + nb) * 512) + (kg * 16 + l15) * 8 + e] = f2bf(sc[k & 127] * w);
    shb[k] = sc[128 + (k & 127)] * w;
    __syncthreads();
    #pragma unroll
    for (int off = 128; off >= 1; off >>= 1) {
        if (k < off) shb[k] += shb[k + off];
        __syncthreads();
    }
    if (k == 0) b1v[n] = b1[n] + shb[0];
}

// ---------------- fused gather + MFMA conv GEMM ----------------
// Gather: group-per-row, ILP-2 (round-12 proven form — ILP-4 thrashed L2,
// r13: FETCH 80->96MB, WRITE 33->48MB). Each 16-lane group owns a row, two
// independent edge chains, int2 LDS edge staging. Fixed edge order + fixed
// even/odd-chain combine = deterministic.

__global__ __launch_bounds__(512, 6) void k_gemm2(
    const unsigned short* __restrict__ hprev, const int* __restrict__ csrc,
    const float* __restrict__ cea, const int* __restrict__ rp,
    const unsigned short* __restrict__ Wtf, const float* __restrict__ bias2,
    const float* __restrict__ brel, const float* __restrict__ wdeg,
    unsigned short* __restrict__ hnext, float* __restrict__ bnpart,
    int nrows, int nblk) {
    __shared__ unsigned short As[128 * 128];
    __shared__ float psb[8 * 64];
    __shared__ float pqb[8 * 64];
    __shared__ int2 ewi[ECAP];
    __shared__ int rps[132];
    const int tid = threadIdx.x;
    const int rb = blockIdx.x * 128;

    const int lane = tid & 63;
    const int wid = tid >> 6;
    const int wm = wid >> 1, wn = wid & 1;

    // stage row bounds + interleaved edge data
    if (tid < 129) {
        int nn = rb + tid;
        rps[tid] = rp[nn < nrows ? nn : nrows];
    }
    __syncthreads();
    const int e0 = rps[0];
    const int ne = rps[128] - e0;
    const bool useLds = (ne <= ECAP);
    if (useLds) {
        for (int i = tid; i < ne; i += 512) {
            ewi[i] = make_int2(csrc[e0 + i], __float_as_int(cea[e0 + i]));
        }
    }

    f32x4 acc[2][4];
    #pragma unroll
    for (int mf = 0; mf < 2; ++mf)
        #pragma unroll
        for (int nf = 0; nf < 4; ++nf) acc[mf][nf] = (f32x4){0.f, 0.f, 0.f, 0.f};

    #pragma unroll
    for (int s = 0; s < 2; ++s) {
        __syncthreads();
        if (s == 0) {
            // ---- gather-staging: group g owns row (wid*16 + rs*4 + g) ----
            const int g = lane >> 4;        // row-within-set 0..3
            const int cl = lane & 15;       // 16B chunk within the row
            #pragma unroll
            for (int rs = 0; rs < 4; ++rs) {
                const int r = wid * 16 + rs * 4 + g;
                const int s0 = rps[r] - e0, s1 = rps[r + 1] - e0;
                float a0 = 0.f, a1 = 0.f, a2 = 0.f, a3 = 0.f,
                      a4 = 0.f, a5 = 0.f, a6 = 0.f, a7 = 0.f;
                float c0 = 0.f, c1 = 0.f, c2 = 0.f, c3 = 0.f,
                      c4 = 0.f, c5 = 0.f, c6 = 0.f, c7 = 0.f;
                for (int i = s0; i < s1; i += 2) {
                    int src1, src2;
                    float w1, w2;
                    const bool has2 = (i + 1) < s1;
                    if (useLds) {
                        const int2 p1 = ewi[i];
                        src1 = p1.x; w1 = __int_as_float(p1.y);
                        const int2 p2 = has2 ? ewi[i + 1] : p1;
                        src2 = p2.x; w2 = has2 ? __int_as_float(p2.y) : 0.f;
                    } else {
                        src1 = csrc[e0 + i]; w1 = cea[e0 + i];
                        src2 = has2 ? csrc[e0 + i + 1] : src1;
                        w2 = has2 ? cea[e0 + i + 1] : 0.f;
                    }
                    const uint4 va = *(const uint4*)(hprev + (size_t)src1 * HID + cl * 8);
                    const uint4 vb = *(const uint4*)(hprev + (size_t)src2 * HID + cl * 8);
                    a0 += bf2f((unsigned short)(va.x)) * w1;
                    a1 += bf2f((unsigned short)(va.x >> 16)) * w1;
                    a2 += bf2f((unsigned short)(va.y)) * w1;
                    a3 += bf2f((unsigned short)(va.y >> 16)) * w1;
                    a4 += bf2f((unsigned short)(va.z)) * w1;
                    a5 += bf2f((unsigned short)(va.z >> 16)) * w1;
                    a6 += bf2f((unsigned short)(va.w)) * w1;
                    a7 += bf2f((unsigned short)(va.w >> 16)) * w1;
                    c0 += bf2f((unsigned short)(vb.x)) * w2;
                    c1 += bf2f((unsigned short)(vb.x >> 16)) * w2;
                    c2 += bf2f((unsigned short)(vb.y)) * w2;
                    c3 += bf2f((unsigned short)(vb.y >> 16)) * w2;
                    c4 += bf2f((unsigned short)(vb.z)) * w2;
                    c5 += bf2f((unsigned short)(vb.z >> 16)) * w2;
                    c6 += bf2f((unsigned short)(vb.w)) * w2;
                    c7 += bf2f((unsigned short)(vb.w >> 16)) * w2;
                }
                // fixed-order combine of the two chains — deterministic
                a0 += c0; a1 += c1; a2 += c2; a3 += c3;
                a4 += c4; a5 += c5; a6 += c6; a7 += c7;
                uint4 o;
                o.x = (unsigned int)f2bf(a0) | ((unsigned int)f2bf(a1) << 16);
                o.y = (unsigned int)f2bf(a2) | ((unsigned int)f2bf(a3) << 16);
                o.z = (unsigned int)f2bf(a4) | ((unsigned int)f2bf(a5) << 16);
                o.w = (unsigned int)f2bf(a6) | ((unsigned int)f2bf(a7) << 16);
                const int p = cl ^ (r & 7);  // swizzled chunk position
                *(uint4*)(As + r * 128 + p * 8) = o;
            }
        } else {
            // ---- contiguous hprev staging (root path) ----
            #pragma unroll
            for (int i = 0; i < 4; ++i) {
                const int r = i * 32 + (tid >> 4);
                const int p = tid & 15;
                const int gr = min(rb + r, nrows - 1);
                const int gc = p ^ (r & 7);
                const uint4 v = *(const uint4*)(hprev + (size_t)gr * 128 + gc * 8);
                *(uint4*)(As + r * 128 + p * 8) = v;
            }
        }
        __syncthreads();
        #pragma unroll
        for (int kk = 0; kk < 4; ++kk) {
            short8 a[2], b[4];
            #pragma unroll
            for (int mf = 0; mf < 2; ++mf) {
                const int r = wm * 32 + mf * 16 + (lane & 15);
                const int p = (kk * 4 + (lane >> 4)) ^ (r & 7);
                a[mf] = *(const short8*)(As + r * 128 + p * 8);
            }
            #pragma unroll
            for (int nf = 0; nf < 4; ++nf) {
                // fragment-linear, coalesced, L2-resident
                b[nf] = *(const short8*)(Wtf + ((size_t)((s * 4 + kk) * 8 + wn * 4 + nf) * 512)
                                               + lane * 8);
            }
            #pragma unroll
            for (int mf = 0; mf < 2; ++mf)
                #pragma unroll
                for (int nf = 0; nf < 4; ++nf)
                    acc[mf][nf] = __builtin_amdgcn_mfma_f32_16x16x32_bf16(
                        a[mf], b[nf], acc[mf][nf], 0, 0, 0);
        }
    }

    // epilogue: bias + wdeg*brel, gelu, direct bf16 store, BN partials
    int colv[4];
    float biasv[4], brelv[4];
    #pragma unroll
    for (int nf = 0; nf < 4; ++nf) {
        colv[nf] = wn * 64 + nf * 16 + (lane & 15);
        biasv[nf] = bias2[colv[nf]];
        brelv[nf] = brel[colv[nf]];
    }
    float ps[4] = {0.f, 0.f, 0.f, 0.f}, pq[4] = {0.f, 0.f, 0.f, 0.f};
    #pragma unroll
    for (int mf = 0; mf < 2; ++mf) {
        #pragma unroll
        for (int reg = 0; reg < 4; ++reg) {
            const int gm = rb + wm * 32 + mf * 16 + (lane >> 4) * 4 + reg;
            const bool valid = gm < nrows;
            const float wd = valid ? wdeg[gm] : 0.f;
            #pragma unroll
            for (int nf = 0; nf < 4; ++nf) {
                const float hv = gelu_f(acc[mf][nf][reg] + biasv[nf] + wd * brelv[nf]);
                if (valid) {
                    hnext[(size_t)gm * 128 + colv[nf]] = f2bf(hv);
                    ps[nf] += hv;
                    pq[nf] += hv * hv;
                }
            }
        }
    }
    #pragma unroll
    for (int nf = 0; nf < 4; ++nf) {
        ps[nf] += __shfl_xor(ps[nf], 16); ps[nf] += __shfl_xor(ps[nf], 32);
        pq[nf] += __shfl_xor(pq[nf], 16); pq[nf] += __shfl_xor(pq[nf], 32);
        if ((lane >> 4) == 0) {
            psb[wid * 64 + nf * 16 + (lane & 15)] = ps[nf];
            pqb[wid * 64 + nf * 16 + (lane & 15)] = pq[nf];
        }
    }
    __syncthreads();
    if (tid < 128) {
        const int wnh = tid >> 6;
        const int c64 = tid & 63;
        float s = 0.f, q = 0.f;
        #pragma unroll
        for (int w = 0; w < 4; ++w) {  // fixed order across waves
            s += psb[(w * 2 + wnh) * 64 + c64];
            q += pqb[(w * 2 + wnh) * 64 + c64];
        }
        bnpart[(size_t)tid * nblk + blockIdx.x] = s;
        bnpart[(size_t)(128 + tid) * nblk + blockIdx.x] = q;
    }
}

// fused parallel deterministic BN reduce + finalize: one block per channel
__global__ void k_bnredfin(const float* __restrict__ bnpart, int nblk,
                           const float* __restrict__ g, const float* __restrict__ b,
                           float* __restrict__ sc) {
    __shared__ float sh[256];
    __shared__ float sh2[256];
    const int tid = threadIdx.x;
    const int col = blockIdx.x;  // 0..127
    float s = 0.f, q = 0.f;
    for (int i = tid; i < nblk; i += 256) {
        s += bnpart[(size_t)col * nblk + i];
        q += bnpart[(size_t)(128 + col) * nblk + i];
    }
    sh[tid] = s;
    sh2[tid] = q;
    __syncthreads();
    #pragma unroll
    for (int off = 128; off >= 1; off >>= 1) {
        if (tid < off) { sh[tid] += sh[tid + off]; sh2[tid] += sh2[tid + off]; }
        __syncthreads();
    }
    if (tid == 0) {
        const float inv_n = 1.0f / (float)NN;
        const float mean = sh[0] * inv_n;
        const float var = sh2[0] * inv_n - mean * mean;
        const float scale = g[col] * rsqrtf(var + BN_EPS);
        sc[col] = scale;
        sc[128 + col] = b[col] - mean * scale;
    }
}

// ---------------- MFMA edge MLP (no Bs staging; deterministic row reduce) ----------------

__global__ __launch_bounds__(512, 6) void k_mlp2(
    const unsigned short* __restrict__ xf, const int* __restrict__ eli,
    const unsigned short* __restrict__ Wtmf, const float* __restrict__ b1v,
    const float* __restrict__ w2, const float* __restrict__ b2,
    float* __restrict__ out, int nq) {
    __shared__ unsigned short As[128 * 128];
    __shared__ int sidx[256];
    __shared__ float rowred2[2][128];
    const int tid = threadIdx.x;
    const int qb = blockIdx.x * 128;
    if (tid < 256) {
        const int rr = tid & 127;
        const int q = qb + rr;
        sidx[tid] = (q < nq) ? eli[(tid >> 7) * NQ + q] : 0;
    }
    __syncthreads();

    const int lane = tid & 63;
    const int wid = tid >> 6;
    const int wm = wid >> 1, wn = wid & 1;

    f32x4 acc[2][4];
    #pragma unroll
    for (int mf = 0; mf < 2; ++mf)
        #pragma unroll
        for (int nf = 0; nf < 4; ++nf) acc[mf][nf] = (f32x4){0.f, 0.f, 0.f, 0.f};

    #pragma unroll
    for (int s = 0; s < 2; ++s) {
        if (s) __syncthreads();
        #pragma unroll
        for (int i = 0; i < 4; ++i) {
            const int r = i * 32 + (tid >> 4);
            const int p = tid & 15;
            const int node = sidx[s * 128 + r];
            const int gc = p ^ (r & 7);
            const uint4 v = *(const uint4*)(xf + (size_t)node * 128 + gc * 8);
            *(uint4*)(As + r * 128 + p * 8) = v;
        }
        __syncthreads();
        #pragma unroll
        for (int kk = 0; kk < 4; ++kk) {
            short8 a[2], b[4];
            #pragma unroll
            for (int mf = 0; mf < 2; ++mf) {
                const int r = wm * 32 + mf * 16 + (lane & 15);
                const int p = (kk * 4 + (lane >> 4)) ^ (r & 7);
                a[mf] = *(const short8*)(As + r * 128 + p * 8);
            }
            #pragma unroll
            for (int nf = 0; nf < 4; ++nf) {
                b[nf] = *(const short8*)(Wtmf + ((size_t)((s * 4 + kk) * 8 + wn * 4 + nf) * 512)
                                               + lane * 8);
            }
            #pragma unroll
            for (int mf = 0; mf < 2; ++mf)
                #pragma unroll
                for (int nf = 0; nf < 4; ++nf)
                    acc[mf][nf] = __builtin_amdgcn_mfma_f32_16x16x32_bf16(
                        a[mf], b[nf], acc[mf][nf], 0, 0, 0);
        }
    }

    int colv[4];
    float w2v[4], b1c[4];
    #pragma unroll
    for (int nf = 0; nf < 4; ++nf) {
        colv[nf] = wn * 64 + nf * 16 + (lane & 15);
        w2v[nf] = w2[colv[nf]];
        b1c[nf] = b1v[colv[nf]];
    }
    #pragma unroll
    for (int mf = 0; mf < 2; ++mf) {
        #pragma unroll
        for (int reg = 0; reg < 4; ++reg) {
            float part = 0.f;
            #pragma unroll
            for (int nf = 0; nf < 4; ++nf)
                part += gelu_f(acc[mf][nf][reg] + b1c[nf]) * w2v[nf];
            part += __shfl_xor(part, 1);
            part += __shfl_xor(part, 2);
            part += __shfl_xor(part, 4);
            part += __shfl_xor(part, 8);
            if ((lane & 15) == 0) {
                const int lr = wm * 32 + mf * 16 + (lane >> 4) * 4 + reg;
                rowred2[wn][lr] = part;  // unique writer per (wn, lr)
            }
        }
    }
    __syncthreads();
    if (tid < 128) {
        const int q = qb + tid;
        if (q < nq)
            out[q] = 1.0f / (1.0f + expf(-(rowred2[0][tid] + rowred2[1][tid] + b2[0])));
    }
}

// ---------------- launcher ----------------

extern "C" void kernel_launch(void* const* d_in, const int* in_sizes, int n_in,
                              void* d_out, int out_size, void* d_ws, size_t ws_size,
                              hipStream_t stream) {
    const float* x_in = (const float*)d_in[0];
    const int* ei = (const int*)d_in[1];
    const float* ea = (const float*)d_in[2];
    const int* eli = (const int*)d_in[3];
    const float* rel_w = (const float*)d_in[4];
    const float* rel_b = (const float*)d_in[5];
    const float* root_w = (const float*)d_in[6];
    const float* bn_g = (const float*)d_in[7];
    const float* bn_b = (const float*)d_in[8];
    const float* w1 = (const float*)d_in[9];
    const float* b1 = (const float*)d_in[10];
    const float* w2 = (const float*)d_in[11];
    const float* b2 = (const float*)d_in[12];
    float* out = (float*)d_out;

    char* ws = (char*)d_ws;
    size_t off = 0;
    auto alloc = [&](size_t bytes) -> void* {
        void* p = ws + off;
        off = (off + bytes + 255) & ~(size_t)255;
        return p;
    };
    const int nblk_gemm = (NN + 127) / 128;  // 782
    unsigned short* hb0 = (unsigned short*)alloc(2ull * NN * HID);
    unsigned short* hb1 = (unsigned short*)alloc(2ull * NN * HID);
    int* eord = (int*)alloc(sizeof(int) * EE);
    int* csrc = (int*)alloc(sizeof(int) * EE);
    float* cea = (float*)alloc(sizeof(float) * EE);
    int* rp = (int*)alloc(sizeof(int) * (NN + 1));
    int* cnt = (int*)alloc(sizeof(int) * NN);
    int* bsum = (int*)alloc(sizeof(int) * 256);
    float* wdeg = (float*)alloc(sizeof(float) * NN);
    float* bnpart = (float*)alloc(sizeof(float) * 256 * (size_t)nblk_gemm);
    float* bnsc = (float*)alloc(sizeof(float) * 256);
    unsigned short* Wtf = (unsigned short*)alloc(2ull * 128 * 256);
    unsigned short* Wtmf = (unsigned short*)alloc(2ull * 128 * 256);
    float* bias2 = (float*)alloc(sizeof(float) * 128);
    float* brel = (float*)alloc(sizeof(float) * 128);
    float* b1v = (float*)alloc(sizeof(float) * 128);
    (void)ws_size;

    const int nb_scan = (NN + 1023) / 1024;

    // CSR count must be zeroed before the fused cvt+hist
    k_zero_int<<<(NN + 255) / 256, 256, 0, stream>>>(cnt, NN);
    // fused input->bf16 convert + degree histogram
    k_cvthist<<<(NN * 64 + 255) / 256, 256, 0, stream>>>(x_in, (unsigned int*)hb0, NN * 64,
                                                         ei, cnt);
    k_scan1<<<nb_scan, 256, 0, stream>>>(cnt, rp, bsum, NN);
    k_scan2<<<1, 256, 0, stream>>>(bsum, nb_scan);
    k_scan3<<<(NN + 255) / 256, 256, 0, stream>>>(rp, bsum, cnt, NN);
    k_fill<<<(EE + 255) / 256, 256, 0, stream>>>(ei, rp, cnt, eord);
    k_sortfill<<<(NN + 255) / 256, 256, 0, stream>>>(ei, ea, rp, eord, csrc, cea, wdeg);
    k_bninit<<<1, 256, 0, stream>>>(bnsc);

    unsigned short* hcur = hb0;
    unsigned short* bufs[2] = {hb1, hb0};
    for (int l = 0; l < NL; ++l) {
        unsigned short* hnext = bufs[l & 1];
        k_wprep<<<128, 256, 0, stream>>>(rel_w + (size_t)l * HID * HID,
                                         root_w + (size_t)l * HID * HID,
                                         rel_b + (size_t)l * HID, bnsc, Wtf, bias2, brel);
        k_gemm2<<<nblk_gemm, 512, 0, stream>>>(hcur, csrc, cea, rp, Wtf, bias2, brel, wdeg,
                                               hnext, bnpart, NN, nblk_gemm);
        k_bnredfin<<<128, 256, 0, stream>>>(bnpart, nblk_gemm,
                                            bn_g + (size_t)l * HID, bn_b + (size_t)l * HID, bnsc);
        hcur = hnext;
    }

    k_mlpprep<<<128, 256, 0, stream>>>(w1, b1, bnsc, Wtmf, b1v);
    k_mlp2<<<(NQ + 127) / 128, 512, 0, stream>>>(hcur, eli, Wtmf, b1v, w2, b2, out, NQ);
}